// Round 1
// baseline (596.093 us; speedup 1.0000x reference)
//
#include <hip/hip_runtime.h>
#include <math.h>

#define N_NODES 20000
#define E_EDGES 320000
#define HID 256
#define OUT_FEAT 128

// ---------------- edge sort (counting sort by dst) ----------------

__global__ void zero_counts_kernel(int* __restrict__ counts, int n) {
    int i = blockIdx.x * 256 + threadIdx.x;
    if (i < n) counts[i] = 0;
}

__global__ void hist_kernel(const int* __restrict__ dst, int* __restrict__ counts) {
    int e = blockIdx.x * 256 + threadIdx.x;
    if (e < E_EDGES) atomicAdd(&counts[dst[e]], 1);
}

// single-block scan over n counts -> exclusive offsets + cursor copy
__global__ void scan_kernel(const int* __restrict__ counts, int* __restrict__ offsets,
                            int* __restrict__ cursor, int n) {
    __shared__ int buf[256];
    __shared__ int carry;
    if (threadIdx.x == 0) carry = 0;
    __syncthreads();
    for (int base = 0; base < n; base += 256) {
        int i = base + (int)threadIdx.x;
        int v = (i < n) ? counts[i] : 0;
        buf[threadIdx.x] = v;
        __syncthreads();
        int val = v;
        for (int off = 1; off < 256; off <<= 1) {
            int t = (threadIdx.x >= (unsigned)off) ? buf[threadIdx.x - off] : 0;
            __syncthreads();
            val += t;
            buf[threadIdx.x] = val;
            __syncthreads();
        }
        int excl = carry + val - v;
        if (i < n) { offsets[i] = excl; cursor[i] = excl; }
        __syncthreads();
        if (threadIdx.x == 255) carry += buf[255];
        __syncthreads();
    }
    if (threadIdx.x == 0) offsets[n] = carry;
}

__global__ void scatter_kernel(const int* __restrict__ src, const int* __restrict__ dst,
                               const float* __restrict__ w, int* __restrict__ cursor,
                               int* __restrict__ ssrc, float* __restrict__ sw) {
    int e = blockIdx.x * 256 + threadIdx.x;
    if (e < E_EDGES) {
        int d = dst[e];
        int p = atomicAdd(&cursor[d], 1);
        ssrc[p] = src[e];
        sw[p] = w[e];
    }
}

// ---------------- aggregation: agg[d] = sum_{e: dst=d} w_e * h[src_e] ----------------

__global__ __launch_bounds__(256) void aggregate_kernel(
    const float* __restrict__ h, const int* __restrict__ offsets,
    const int* __restrict__ ssrc, const float* __restrict__ sw,
    float* __restrict__ agg) {
    int d = blockIdx.x;
    int t = threadIdx.x;                    // feature column, 0..255
    int beg = offsets[d], end = offsets[d + 1];
    float acc = 0.f;
    for (int j = beg; j < end; ++j) {
        int s = ssrc[j];
        float wv = sw[j];
        acc = fmaf(h[(size_t)s * HID + t], wv, acc);
    }
    agg[(size_t)d * HID + t] = acc;
}

// ---------------- fp32 GEMM: C[M,Nn] = A1@W[:, :256]^T (+ A2@W[:,256:512]^T) (+bias, relu, residual) ----------------
// BM=128, BN=64, BK=16, 256 threads, TM=8, TN=4

#define BM 128
#define BN 64
#define BK 16
#define ASTRIDE 132   // BM + 4 pad
#define WSTRIDE 68    // BN + 4 pad

enum { EPI_PLAIN = 0, EPI_GCONV = 1 };

template <int EPI>
__global__ __launch_bounds__(256) void gemm_kernel(
    const float* __restrict__ A1,      // [M,256]
    const float* __restrict__ A2,      // [M,256] or nullptr
    const float* __restrict__ W,       // [Nn, w_stride] row-major
    int w_stride,
    const float* __restrict__ bias,    // [Nn] or nullptr
    const float* __restrict__ Hres,    // [M,256] residual (EPI_GCONV)
    float* __restrict__ Out,           // [M, ldo]
    int M, int ldo) {
    __shared__ float As[BK][ASTRIDE];
    __shared__ float Ws[BK][WSTRIDE];

    const int tid = threadIdx.x;
    const int tx = tid & 15;   // col group: cols tx*4 .. tx*4+3
    const int ty = tid >> 4;   // row group: rows ty*8 .. ty*8+7
    const int row0 = blockIdx.y * BM;
    const int col0 = blockIdx.x * BN;

    float acc[8][4];
#pragma unroll
    for (int i = 0; i < 8; i++)
#pragma unroll
        for (int j = 0; j < 4; j++) acc[i][j] = 0.f;

    const int nseg = (A2 != nullptr) ? 2 : 1;
    for (int seg = 0; seg < nseg; ++seg) {
        const float* Aq = (seg == 0) ? A1 : A2;
        for (int kt = 0; kt < 256; kt += BK) {
            const int kglob = seg * 256 + kt;
            // A tile: 128 rows x 16 k = 512 float4, 2 per thread
#pragma unroll
            for (int l = 0; l < 2; ++l) {
                int idx = tid + l * 256;
                int r = idx >> 2;             // 0..127
                int kc = (idx & 3) * 4;       // 0,4,8,12
                int grow = row0 + r;
                float4 av = make_float4(0.f, 0.f, 0.f, 0.f);
                if (grow < M) av = *(const float4*)(Aq + (size_t)grow * 256 + kt + kc);
                As[kc + 0][r] = av.x;
                As[kc + 1][r] = av.y;
                As[kc + 2][r] = av.z;
                As[kc + 3][r] = av.w;
            }
            // W tile: 64 rows x 16 k = 256 float4, 1 per thread
            {
                int r = tid >> 2;             // 0..63
                int kc = (tid & 3) * 4;
                const float4 wv = *(const float4*)(W + (size_t)(col0 + r) * w_stride + kglob + kc);
                Ws[kc + 0][r] = wv.x;
                Ws[kc + 1][r] = wv.y;
                Ws[kc + 2][r] = wv.z;
                Ws[kc + 3][r] = wv.w;
            }
            __syncthreads();
#pragma unroll
            for (int kk = 0; kk < BK; ++kk) {
                float a[8], b[4];
                *(float4*)&a[0] = *(const float4*)&As[kk][ty * 8];
                *(float4*)&a[4] = *(const float4*)&As[kk][ty * 8 + 4];
                *(float4*)&b[0] = *(const float4*)&Ws[kk][tx * 4];
#pragma unroll
                for (int i = 0; i < 8; i++)
#pragma unroll
                    for (int j = 0; j < 4; j++)
                        acc[i][j] = fmaf(a[i], b[j], acc[i][j]);
            }
            __syncthreads();
        }
    }

    // epilogue
    const int ncol = col0 + tx * 4;
#pragma unroll
    for (int i = 0; i < 8; i++) {
        int m = row0 + ty * 8 + i;
        if (m >= M) continue;
        float4 v = make_float4(acc[i][0], acc[i][1], acc[i][2], acc[i][3]);
        if (EPI == EPI_GCONV) {
            const float4 b4 = *(const float4*)(bias + ncol);
            const float4 r4 = *(const float4*)(Hres + (size_t)m * 256 + ncol);
            v.x = r4.x + fmaxf(v.x + b4.x, 0.f);
            v.y = r4.y + fmaxf(v.y + b4.y, 0.f);
            v.z = r4.z + fmaxf(v.z + b4.z, 0.f);
            v.w = r4.w + fmaxf(v.w + b4.w, 0.f);
        }
        *(float4*)(Out + (size_t)m * ldo + ncol) = v;
    }
}

// ---------------- row L2-normalize d_out [N,128] in place ----------------

__global__ void normalize_kernel(float* __restrict__ out) {
    int row = blockIdx.x;
    int t = threadIdx.x;  // 64 threads
    float v0 = out[(size_t)row * OUT_FEAT + t];
    float v1 = out[(size_t)row * OUT_FEAT + t + 64];
    float s = v0 * v0 + v1 * v1;
#pragma unroll
    for (int off = 32; off > 0; off >>= 1) s += __shfl_xor(s, off);
    float inv = 1.0f / sqrtf(s);
    out[(size_t)row * OUT_FEAT + t] = v0 * inv;
    out[(size_t)row * OUT_FEAT + t + 64] = v1 * inv;
}

// ---------------- launch ----------------

extern "C" void kernel_launch(void* const* d_in, const int* in_sizes, int n_in,
                              void* d_out, int out_size, void* d_ws, size_t ws_size,
                              hipStream_t stream) {
    const float* x        = (const float*)d_in[0];
    const int*   edge_src = (const int*)d_in[1];
    const int*   edge_dst = (const int*)d_in[2];
    const float* edge_w   = (const float*)d_in[3];
    const float* W_emb    = (const float*)d_in[4];
    const float* W_gc1    = (const float*)d_in[5];
    const float* b_gc1    = (const float*)d_in[6];
    const float* W_gc2    = (const float*)d_in[7];
    const float* b_gc2    = (const float*)d_in[8];
    const float* W_fc     = (const float*)d_in[9];
    float* out = (float*)d_out;

    // workspace layout
    float* hA = (float*)d_ws;                      // N*256
    float* hB = hA + (size_t)N_NODES * HID;        // N*256
    float* agg = hB + (size_t)N_NODES * HID;       // N*256
    float* sorted_w = agg + (size_t)N_NODES * HID; // E
    int* sorted_src = (int*)(sorted_w + E_EDGES);  // E
    int* offsets = sorted_src + E_EDGES;           // N+1
    int* cursor = offsets + N_NODES + 1;           // N
    int* counts = cursor + N_NODES;                // N

    const int eb = (E_EDGES + 255) / 256;
    const int nb = (N_NODES + 255) / 256;

    // build CSR-by-dst (inputs re-poisoned each call, so rebuild every launch)
    zero_counts_kernel<<<nb, 256, 0, stream>>>(counts, N_NODES);
    hist_kernel<<<eb, 256, 0, stream>>>(edge_dst, counts);
    scan_kernel<<<1, 256, 0, stream>>>(counts, offsets, cursor, N_NODES);
    scatter_kernel<<<eb, 256, 0, stream>>>(edge_src, edge_dst, edge_w, cursor, sorted_src, sorted_w);

    const dim3 blk(256);
    const dim3 grid_h(HID / BN, (N_NODES + BM - 1) / BM);       // 4 x 157
    const dim3 grid_fc(OUT_FEAT / BN, (N_NODES + BM - 1) / BM); // 2 x 157

    // h0 = x @ W_emb^T
    gemm_kernel<EPI_PLAIN><<<grid_h, blk, 0, stream>>>(x, nullptr, W_emb, 256, nullptr, nullptr,
                                                       hA, N_NODES, HID);
    // agg1 = A @ h0
    aggregate_kernel<<<N_NODES, 256, 0, stream>>>(hA, offsets, sorted_src, sorted_w, agg);
    // h1 = h0 + relu(h0@Wl1^T + agg1@Wr1^T + b1)  -> hB
    gemm_kernel<EPI_GCONV><<<grid_h, blk, 0, stream>>>(hA, agg, W_gc1, 512, b_gc1, hA,
                                                       hB, N_NODES, HID);
    // agg2 = A @ h1
    aggregate_kernel<<<N_NODES, 256, 0, stream>>>(hB, offsets, sorted_src, sorted_w, agg);
    // h2 = h1 + relu(h1@Wl2^T + agg2@Wr2^T + b2)  -> hA
    gemm_kernel<EPI_GCONV><<<grid_h, blk, 0, stream>>>(hB, agg, W_gc2, 512, b_gc2, hB,
                                                       hA, N_NODES, HID);
    // out_raw = h2 @ W_fc^T
    gemm_kernel<EPI_PLAIN><<<grid_fc, blk, 0, stream>>>(hA, nullptr, W_fc, 256, nullptr, nullptr,
                                                        out, N_NODES, OUT_FEAT);
    // row normalize
    normalize_kernel<<<N_NODES, 64, 0, stream>>>(out);
}

// Round 2
// 348.217 us; speedup vs baseline: 1.7118x; 1.7118x over previous
//
#include <hip/hip_runtime.h>
#include <math.h>

#define N_NODES 20000
#define E_EDGES 320000
#define HID 256
#define OUT_FEAT 128
#define MPAD 20224           // 79 * 256
#define NBLK 79              // ceil(20000/256)

typedef __attribute__((ext_vector_type(8))) __bf16 bf16x8;
typedef __attribute__((ext_vector_type(4))) __bf16 bf16x4;
typedef __attribute__((ext_vector_type(4))) float floatx4;

// ---------------- CSR build (counting sort by dst) ----------------

__global__ void zero_counts_kernel(int* __restrict__ counts) {
    int i = blockIdx.x * 256 + threadIdx.x;
    if (i < N_NODES) counts[i] = 0;
}

__global__ void hist_kernel(const int* __restrict__ dst, int* __restrict__ counts) {
    int e = blockIdx.x * 256 + threadIdx.x;
    if (e < E_EDGES) atomicAdd(&counts[dst[e]], 1);
}

__global__ void scan1_kernel(const int* __restrict__ counts, int* __restrict__ offsets,
                             int* __restrict__ bsum) {
    __shared__ int buf[256];
    int t = threadIdx.x;
    int i = blockIdx.x * 256 + t;
    int v = (i < N_NODES) ? counts[i] : 0;
    buf[t] = v;
    __syncthreads();
    int val = v;
    for (int off = 1; off < 256; off <<= 1) {
        int tv = (t >= off) ? buf[t - off] : 0;
        __syncthreads();
        val += tv;
        buf[t] = val;
        __syncthreads();
    }
    if (i < N_NODES) offsets[i] = val - v;   // exclusive within block
    if (t == 255) bsum[blockIdx.x] = val;
}

__global__ void scan2_kernel(int* __restrict__ bsum) {
    __shared__ int buf[256];
    int t = threadIdx.x;
    int v = (t < NBLK) ? bsum[t] : 0;
    buf[t] = v;
    __syncthreads();
    int val = v;
    for (int off = 1; off < 256; off <<= 1) {
        int tv = (t >= off) ? buf[t - off] : 0;
        __syncthreads();
        val += tv;
        buf[t] = val;
        __syncthreads();
    }
    if (t < NBLK) bsum[t] = val - v;         // exclusive across blocks
}

__global__ void scan3_kernel(int* __restrict__ offsets, int* __restrict__ cursor,
                             const int* __restrict__ bsum) {
    int i = blockIdx.x * 256 + threadIdx.x;
    if (i < N_NODES) {
        int o = offsets[i] + bsum[blockIdx.x];
        offsets[i] = o;
        cursor[i] = o;
    }
    if (i == 0) offsets[N_NODES] = E_EDGES;
}

__global__ void scatter_kernel(const int* __restrict__ src, const int* __restrict__ dst,
                               const float* __restrict__ w, int* __restrict__ cursor,
                               int2* __restrict__ edges) {
    int e = blockIdx.x * 256 + threadIdx.x;
    if (e < E_EDGES) {
        int d = dst[e];
        int p = atomicAdd(&cursor[d], 1);
        edges[p] = make_int2(src[e], __float_as_int(w[e]));
    }
}

// ---------------- fp32 -> bf16 conversions ----------------

// x [20000,256] f32 -> xb [MPAD,256] bf16 (pad rows zeroed)
__global__ void convert_x_kernel(const float* __restrict__ x, __bf16* __restrict__ xb) {
    size_t i = ((size_t)blockIdx.x * 256 + threadIdx.x) * 8;
    float4 v0 = make_float4(0.f, 0.f, 0.f, 0.f), v1 = v0;
    if (i < (size_t)N_NODES * HID) {
        v0 = *(const float4*)(x + i);
        v1 = *(const float4*)(x + i + 4);
    }
    bf16x8 o;
    o[0] = (__bf16)v0.x; o[1] = (__bf16)v0.y; o[2] = (__bf16)v0.z; o[3] = (__bf16)v0.w;
    o[4] = (__bf16)v1.x; o[5] = (__bf16)v1.y; o[6] = (__bf16)v1.z; o[7] = (__bf16)v1.w;
    *(bf16x8*)(xb + i) = o;
}

// all four weight matrices in one kernel
__global__ void convert_w_kernel(const float* __restrict__ w0, const float* __restrict__ w1,
                                 const float* __restrict__ w2, const float* __restrict__ w3,
                                 __bf16* __restrict__ o0, __bf16* __restrict__ o1,
                                 __bf16* __restrict__ o2, __bf16* __restrict__ o3) {
    size_t gi = ((size_t)blockIdx.x * 256 + threadIdx.x) * 8;
    const size_t s0 = 65536, s1 = s0 + 131072, s2 = s1 + 131072, s3 = s2 + 32768;
    const float* src; __bf16* dst; size_t off;
    if (gi < s0)      { src = w0; dst = o0; off = gi; }
    else if (gi < s1) { src = w1; dst = o1; off = gi - s0; }
    else if (gi < s2) { src = w2; dst = o2; off = gi - s1; }
    else if (gi < s3) { src = w3; dst = o3; off = gi - s2; }
    else return;
    float4 v0 = *(const float4*)(src + off);
    float4 v1 = *(const float4*)(src + off + 4);
    bf16x8 o;
    o[0] = (__bf16)v0.x; o[1] = (__bf16)v0.y; o[2] = (__bf16)v0.z; o[3] = (__bf16)v0.w;
    o[4] = (__bf16)v1.x; o[5] = (__bf16)v1.y; o[6] = (__bf16)v1.z; o[7] = (__bf16)v1.w;
    *(bf16x8*)(dst + off) = o;
}

// ---------------- aggregation: agg[d] = sum_e w_e * h[src_e]  (bf16 in/out, fp32 acc) ----------------

__global__ __launch_bounds__(256) void aggregate_kernel(
    const __bf16* __restrict__ h, const int* __restrict__ offsets,
    const int2* __restrict__ edges, __bf16* __restrict__ agg) {
    int w = threadIdx.x >> 6, l = threadIdx.x & 63;
    int d = blockIdx.x * 4 + w;
    int beg = offsets[d], end = offsets[d + 1];
    float a0 = 0.f, a1 = 0.f, a2 = 0.f, a3 = 0.f;
    for (int j = beg; j < end; ++j) {
        int2 e = edges[j];
        float wv = __int_as_float(e.y);
        bf16x4 hv = *(const bf16x4*)(h + (size_t)e.x * HID + l * 4);
        a0 = fmaf(wv, (float)hv[0], a0);
        a1 = fmaf(wv, (float)hv[1], a1);
        a2 = fmaf(wv, (float)hv[2], a2);
        a3 = fmaf(wv, (float)hv[3], a3);
    }
    bf16x4 o;
    o[0] = (__bf16)a0; o[1] = (__bf16)a1; o[2] = (__bf16)a2; o[3] = (__bf16)a3;
    *(bf16x4*)(agg + (size_t)d * HID + l * 4) = o;
}

// ---------------- LDS-free MFMA GEMM: C[M,N] = [A1|A2] @ W^T ----------------
// block = 256 thr = 4 waves stacked in M; wave tile 64x64 (4x4 MFMA 16x16x32).
// EPI: 0 = EMB (write hf f32 + hb bf16), 1 = GCONV (hf += relu(acc+bias), write hb2), 2 = FC (write f32 out, ld=128)

template <int KTOT, int EPI>
__global__ __launch_bounds__(256) void mfma_gemm_kernel(
    const __bf16* __restrict__ A1,   // [MPAD,256]
    const __bf16* __restrict__ A2,   // [MPAD,256] (KTOT==512) or unused
    const __bf16* __restrict__ W,    // [N,KTOT]
    const float* __restrict__ bias,  // [N] (GCONV)
    float* __restrict__ hf,          // f32 master h (EMB: out, GCONV: in/out)
    __bf16* __restrict__ outb,       // bf16 h out (EMB/GCONV)
    float* __restrict__ outf)        // FC out [M,128]
{
    const int tid = threadIdx.x;
    const int wv = tid >> 6;
    const int l = tid & 63;
    const int lr = l & 15;
    const int lq = l >> 4;
    const int row0 = blockIdx.y * 256 + wv * 64;
    const int col0 = blockIdx.x * 64;

    floatx4 acc[4][4];
#pragma unroll
    for (int i = 0; i < 4; i++)
#pragma unroll
        for (int j = 0; j < 4; j++) acc[i][j] = (floatx4){0.f, 0.f, 0.f, 0.f};

#pragma unroll
    for (int kt = 0; kt < KTOT; kt += 32) {
        const __bf16* Aseg = (KTOT == 512 && kt >= 256) ? A2 : A1;
        const int ka = (KTOT == 512) ? (kt & 255) : kt;
        bf16x8 af[4], bf[4];
#pragma unroll
        for (int mt = 0; mt < 4; mt++)
            af[mt] = *(const bf16x8*)(Aseg + (size_t)(row0 + mt * 16 + lr) * 256 + ka + lq * 8);
#pragma unroll
        for (int nt = 0; nt < 4; nt++)
            bf[nt] = *(const bf16x8*)(W + (size_t)(col0 + nt * 16 + lr) * KTOT + kt + lq * 8);
#pragma unroll
        for (int mt = 0; mt < 4; mt++)
#pragma unroll
            for (int nt = 0; nt < 4; nt++)
                acc[mt][nt] = __builtin_amdgcn_mfma_f32_16x16x32_bf16(af[mt], bf[nt], acc[mt][nt], 0, 0, 0);
    }

    // epilogue: C/D layout col = lane&15, row = (lane>>4)*4 + reg
#pragma unroll
    for (int nt = 0; nt < 4; nt++) {
        const int ecol = col0 + nt * 16 + lr;
        float b = 0.f;
        if (EPI == 1) b = bias[ecol];
#pragma unroll
        for (int mt = 0; mt < 4; mt++) {
#pragma unroll
            for (int r = 0; r < 4; r++) {
                int erow = row0 + mt * 16 + lq * 4 + r;
                if (erow >= N_NODES) continue;
                float v = acc[mt][nt][r];
                if (EPI == 0) {
                    hf[(size_t)erow * HID + ecol] = v;
                    outb[(size_t)erow * HID + ecol] = (__bf16)v;
                } else if (EPI == 1) {
                    float res = hf[(size_t)erow * HID + ecol];
                    v = res + fmaxf(v + b, 0.f);
                    hf[(size_t)erow * HID + ecol] = v;
                    outb[(size_t)erow * HID + ecol] = (__bf16)v;
                } else {
                    outf[(size_t)erow * OUT_FEAT + ecol] = v;
                }
            }
        }
    }
}

// ---------------- row L2-normalize out [20000,128] in place ----------------

__global__ __launch_bounds__(256) void normalize_kernel(float* __restrict__ out) {
    int w = threadIdx.x >> 6, l = threadIdx.x & 63;
    int row = blockIdx.x * 4 + w;
    float v0 = out[(size_t)row * OUT_FEAT + l];
    float v1 = out[(size_t)row * OUT_FEAT + 64 + l];
    float s = v0 * v0 + v1 * v1;
#pragma unroll
    for (int off = 32; off > 0; off >>= 1) s += __shfl_xor(s, off);
    float inv = 1.0f / sqrtf(s);
    out[(size_t)row * OUT_FEAT + l] = v0 * inv;
    out[(size_t)row * OUT_FEAT + 64 + l] = v1 * inv;
}

// ---------------- launch ----------------

extern "C" void kernel_launch(void* const* d_in, const int* in_sizes, int n_in,
                              void* d_out, int out_size, void* d_ws, size_t ws_size,
                              hipStream_t stream) {
    const float* x        = (const float*)d_in[0];
    const int*   edge_src = (const int*)d_in[1];
    const int*   edge_dst = (const int*)d_in[2];
    const float* edge_w   = (const float*)d_in[3];
    const float* W_emb    = (const float*)d_in[4];
    const float* W_gc1    = (const float*)d_in[5];
    const float* b_gc1    = (const float*)d_in[6];
    const float* W_gc2    = (const float*)d_in[7];
    const float* b_gc2    = (const float*)d_in[8];
    const float* W_fc     = (const float*)d_in[9];
    float* out = (float*)d_out;

    // ---- workspace layout (all 256B-aligned slices) ----
    char* p = (char*)d_ws;
    const size_t HROW = (size_t)MPAD * HID;
    float*  hf    = (float*)p;              p += HROW * 4;        // f32 master h (in-place residual)
    __bf16* hb0   = (__bf16*)p;             p += HROW * 2;        // h0 bf16, later h2 bf16
    __bf16* hb1   = (__bf16*)p;             p += HROW * 2;        // h1 bf16
    __bf16* xbagg = (__bf16*)p;             p += HROW * 2;        // x bf16, later agg bf16
    __bf16* wemb  = (__bf16*)p;             p += 65536 * 2;
    __bf16* w1b   = (__bf16*)p;             p += 131072 * 2;
    __bf16* w2b   = (__bf16*)p;             p += 131072 * 2;
    __bf16* wfcb  = (__bf16*)p;             p += 32768 * 2;
    int2*   edges = (int2*)p;               p += (size_t)E_EDGES * 8;
    int*    offsets = (int*)p;              p += (N_NODES + 8) * 4;
    int*    cursor  = (int*)p;              p += N_NODES * 4;
    int*    counts  = (int*)p;              p += N_NODES * 4;
    int*    bsum    = (int*)p;              p += 256 * 4;

    const int eb = (E_EDGES + 255) / 256;

    // CSR build
    zero_counts_kernel<<<NBLK, 256, 0, stream>>>(counts);
    hist_kernel<<<eb, 256, 0, stream>>>(edge_dst, counts);
    scan1_kernel<<<NBLK, 256, 0, stream>>>(counts, offsets, bsum);
    scan2_kernel<<<1, 256, 0, stream>>>(bsum);
    scan3_kernel<<<NBLK, 256, 0, stream>>>(offsets, cursor, bsum);
    scatter_kernel<<<eb, 256, 0, stream>>>(edge_src, edge_dst, edge_w, cursor, edges);

    // conversions
    convert_w_kernel<<<176, 256, 0, stream>>>(W_emb, W_gc1, W_gc2, W_fc, wemb, w1b, w2b, wfcb);
    convert_x_kernel<<<(int)(HROW / (256 * 8)), 256, 0, stream>>>(x, xbagg);

    const dim3 blk(256);
    const dim3 grid_h(HID / 64, NBLK);       // 4 x 79
    const dim3 grid_fc(OUT_FEAT / 64, NBLK); // 2 x 79

    // h0 = x @ W_emb^T  -> hf (f32), hb0 (bf16)
    mfma_gemm_kernel<256, 0><<<grid_h, blk, 0, stream>>>(xbagg, nullptr, wemb, nullptr, hf, hb0, nullptr);
    // agg1 = A @ h0 -> xbagg (x dead now)
    aggregate_kernel<<<N_NODES / 4, blk, 0, stream>>>(hb0, offsets, edges, xbagg);
    // h1 = h0 + relu([h0|agg1] @ W1^T + b1): hf in-place, bf16 -> hb1
    mfma_gemm_kernel<512, 1><<<grid_h, blk, 0, stream>>>(hb0, xbagg, w1b, b_gc1, hf, hb1, nullptr);
    // agg2 = A @ h1 -> xbagg
    aggregate_kernel<<<N_NODES / 4, blk, 0, stream>>>(hb1, offsets, edges, xbagg);
    // h2 = h1 + relu([h1|agg2] @ W2^T + b2): hf in-place, bf16 -> hb0
    mfma_gemm_kernel<512, 1><<<grid_h, blk, 0, stream>>>(hb1, xbagg, w2b, b_gc2, hf, hb0, nullptr);
    // out = h2 @ W_fc^T
    mfma_gemm_kernel<256, 2><<<grid_fc, blk, 0, stream>>>(hb0, nullptr, wfcb, nullptr, nullptr, nullptr, out);
    // normalize rows
    normalize_kernel<<<N_NODES / 4, blk, 0, stream>>>(out);
}

// Round 3
// 295.262 us; speedup vs baseline: 2.0189x; 1.1793x over previous
//
#include <hip/hip_runtime.h>
#include <math.h>

#define N_NODES 20000
#define E_EDGES 320000
#define HID 256
#define OUT_FEAT 128
#define MPAD 20224           // 158 * 128
#define NBLK 79              // ceil(20000/256)

typedef __attribute__((ext_vector_type(8))) __bf16 bf16x8;
typedef __attribute__((ext_vector_type(4))) __bf16 bf16x4;
typedef __attribute__((ext_vector_type(4))) float floatx4;

// ---------------- CSR build (counting sort by dst) ----------------

__global__ void zero_counts_kernel(int* __restrict__ counts) {
    int i = blockIdx.x * 256 + threadIdx.x;
    if (i < N_NODES) counts[i] = 0;
}

__global__ void hist_kernel(const int* __restrict__ dst, int* __restrict__ counts) {
    int e = blockIdx.x * 256 + threadIdx.x;
    if (e < E_EDGES) atomicAdd(&counts[dst[e]], 1);
}

__global__ void scan1_kernel(const int* __restrict__ counts, int* __restrict__ offsets,
                             int* __restrict__ bsum) {
    __shared__ int buf[256];
    int t = threadIdx.x;
    int i = blockIdx.x * 256 + t;
    int v = (i < N_NODES) ? counts[i] : 0;
    buf[t] = v;
    __syncthreads();
    int val = v;
    for (int off = 1; off < 256; off <<= 1) {
        int tv = (t >= off) ? buf[t - off] : 0;
        __syncthreads();
        val += tv;
        buf[t] = val;
        __syncthreads();
    }
    if (i < N_NODES) offsets[i] = val - v;   // exclusive within block
    if (t == 255) bsum[blockIdx.x] = val;
}

__global__ void scan2_kernel(int* __restrict__ bsum) {
    __shared__ int buf[256];
    int t = threadIdx.x;
    int v = (t < NBLK) ? bsum[t] : 0;
    buf[t] = v;
    __syncthreads();
    int val = v;
    for (int off = 1; off < 256; off <<= 1) {
        int tv = (t >= off) ? buf[t - off] : 0;
        __syncthreads();
        val += tv;
        buf[t] = val;
        __syncthreads();
    }
    if (t < NBLK) bsum[t] = val - v;         // exclusive across blocks
}

__global__ void scan3_kernel(int* __restrict__ offsets, int* __restrict__ cursor,
                             const int* __restrict__ bsum) {
    int i = blockIdx.x * 256 + threadIdx.x;
    if (i < N_NODES) {
        int o = offsets[i] + bsum[blockIdx.x];
        offsets[i] = o;
        cursor[i] = o;
    }
    if (i == 0) offsets[N_NODES] = E_EDGES;
}

__global__ void scatter_kernel(const int* __restrict__ src, const int* __restrict__ dst,
                               const float* __restrict__ w, int* __restrict__ cursor,
                               int2* __restrict__ edges) {
    int e = blockIdx.x * 256 + threadIdx.x;
    if (e < E_EDGES) {
        int d = dst[e];
        int p = atomicAdd(&cursor[d], 1);
        edges[p] = make_int2(src[e], __float_as_int(w[e]));
    }
}

// ---------------- weight fp32 -> bf16 (all four in one kernel) ----------------

__global__ void convert_w_kernel(const float* __restrict__ w0, const float* __restrict__ w1,
                                 const float* __restrict__ w2, const float* __restrict__ w3,
                                 __bf16* __restrict__ o0, __bf16* __restrict__ o1,
                                 __bf16* __restrict__ o2, __bf16* __restrict__ o3) {
    size_t gi = ((size_t)blockIdx.x * 256 + threadIdx.x) * 8;
    const size_t s0 = 65536, s1 = s0 + 131072, s2 = s1 + 131072, s3 = s2 + 32768;
    const float* src; __bf16* dst; size_t off;
    if (gi < s0)      { src = w0; dst = o0; off = gi; }
    else if (gi < s1) { src = w1; dst = o1; off = gi - s0; }
    else if (gi < s2) { src = w2; dst = o2; off = gi - s1; }
    else if (gi < s3) { src = w3; dst = o3; off = gi - s2; }
    else return;
    float4 v0 = *(const float4*)(src + off);
    float4 v1 = *(const float4*)(src + off + 4);
    bf16x8 o;
    o[0] = (__bf16)v0.x; o[1] = (__bf16)v0.y; o[2] = (__bf16)v0.z; o[3] = (__bf16)v0.w;
    o[4] = (__bf16)v1.x; o[5] = (__bf16)v1.y; o[6] = (__bf16)v1.z; o[7] = (__bf16)v1.w;
    *(bf16x8*)(dst + off) = o;
}

// ---------------- aggregation: agg[d] = sum_e w_e * h[src_e]  (bf16 in/out, fp32 acc) ----------------

__global__ __launch_bounds__(256) void aggregate_kernel(
    const __bf16* __restrict__ h, const int* __restrict__ offsets,
    const int2* __restrict__ edges, __bf16* __restrict__ agg) {
    int w = threadIdx.x >> 6, l = threadIdx.x & 63;
    int d = blockIdx.x * 4 + w;
    int beg = offsets[d], end = offsets[d + 1];
    float a0 = 0.f, a1 = 0.f, a2 = 0.f, a3 = 0.f;
    int j = beg;
    for (; j + 2 <= end; j += 2) {
        int2 e0 = edges[j];
        int2 e1 = edges[j + 1];
        bf16x4 h0 = *(const bf16x4*)(h + (size_t)e0.x * HID + l * 4);
        bf16x4 h1 = *(const bf16x4*)(h + (size_t)e1.x * HID + l * 4);
        float w0 = __int_as_float(e0.y), w1 = __int_as_float(e1.y);
        a0 = fmaf(w0, (float)h0[0], a0); a1 = fmaf(w0, (float)h0[1], a1);
        a2 = fmaf(w0, (float)h0[2], a2); a3 = fmaf(w0, (float)h0[3], a3);
        a0 = fmaf(w1, (float)h1[0], a0); a1 = fmaf(w1, (float)h1[1], a1);
        a2 = fmaf(w1, (float)h1[2], a2); a3 = fmaf(w1, (float)h1[3], a3);
    }
    if (j < end) {
        int2 e0 = edges[j];
        bf16x4 h0 = *(const bf16x4*)(h + (size_t)e0.x * HID + l * 4);
        float w0 = __int_as_float(e0.y);
        a0 = fmaf(w0, (float)h0[0], a0); a1 = fmaf(w0, (float)h0[1], a1);
        a2 = fmaf(w0, (float)h0[2], a2); a3 = fmaf(w0, (float)h0[3], a3);
    }
    bf16x4 o;
    o[0] = (__bf16)a0; o[1] = (__bf16)a1; o[2] = (__bf16)a2; o[3] = (__bf16)a3;
    *(bf16x4*)(agg + (size_t)d * HID + l * 4) = o;
}

// ---------------- emb GEMM: h0 = x @ Wemb^T (f32 A in, bf16 out) ----------------
// block 256 thr = 4 waves (2 in M x 2 in N); wave tile 32x64; block tile 64x128.

__global__ __launch_bounds__(256) void emb_gemm_kernel(
    const float* __restrict__ x,       // [20000,256] f32
    const __bf16* __restrict__ W,      // [256,256] bf16
    __bf16* __restrict__ hb)           // [MPAD,256] bf16
{
    const int tid = threadIdx.x;
    const int wv = tid >> 6;
    const int l = tid & 63;
    const int lr = l & 15;
    const int lq = l >> 4;
    const int wm = wv & 1, wn = wv >> 1;
    const int rowbase = blockIdx.y * 64 + wm * 32;
    const int colbase = blockIdx.x * 128 + wn * 64;

    floatx4 acc[2][4];
#pragma unroll
    for (int i = 0; i < 2; i++)
#pragma unroll
        for (int j = 0; j < 4; j++) acc[i][j] = (floatx4){0.f, 0.f, 0.f, 0.f};

#pragma unroll
    for (int kt = 0; kt < 256; kt += 32) {
        bf16x8 af[2], bfr[4];
#pragma unroll
        for (int mt = 0; mt < 2; mt++) {
            int row = rowbase + mt * 16 + lr;
            float4 v0 = make_float4(0.f, 0.f, 0.f, 0.f), v1 = v0;
            if (row < N_NODES) {
                const float* xp = x + (size_t)row * 256 + kt + lq * 8;
                v0 = *(const float4*)xp;
                v1 = *(const float4*)(xp + 4);
            }
            bf16x8 a;
            a[0] = (__bf16)v0.x; a[1] = (__bf16)v0.y; a[2] = (__bf16)v0.z; a[3] = (__bf16)v0.w;
            a[4] = (__bf16)v1.x; a[5] = (__bf16)v1.y; a[6] = (__bf16)v1.z; a[7] = (__bf16)v1.w;
            af[mt] = a;
        }
#pragma unroll
        for (int nt = 0; nt < 4; nt++)
            bfr[nt] = *(const bf16x8*)(W + (size_t)(colbase + nt * 16 + lr) * 256 + kt + lq * 8);
#pragma unroll
        for (int mt = 0; mt < 2; mt++)
#pragma unroll
            for (int nt = 0; nt < 4; nt++)
                acc[mt][nt] = __builtin_amdgcn_mfma_f32_16x16x32_bf16(af[mt], bfr[nt], acc[mt][nt], 0, 0, 0);
    }

#pragma unroll
    for (int nt = 0; nt < 4; nt++) {
        const int col = colbase + nt * 16 + lr;
#pragma unroll
        for (int mt = 0; mt < 2; mt++)
#pragma unroll
            for (int r = 0; r < 4; r++) {
                int row = rowbase + mt * 16 + lq * 4 + r;
                if (row < N_NODES)
                    hb[(size_t)row * HID + col] = (__bf16)acc[mt][nt][r];
            }
    }
}

// ---------------- gconv GEMM: hn = hp + relu([hp|agg] @ W^T + b) (all bf16, f32 acc) ----------------

__global__ __launch_bounds__(256) void gconv_gemm_kernel(
    const __bf16* __restrict__ hp,     // [MPAD,256] bf16 (A1 + residual)
    const __bf16* __restrict__ ag,     // [MPAD,256] bf16 (A2)
    const __bf16* __restrict__ W,      // [256,512] bf16
    const float* __restrict__ bias,    // [256] f32
    __bf16* __restrict__ hn)           // [MPAD,256] bf16
{
    const int tid = threadIdx.x;
    const int wv = tid >> 6;
    const int l = tid & 63;
    const int lr = l & 15;
    const int lq = l >> 4;
    const int wm = wv & 1, wn = wv >> 1;
    const int rowbase = blockIdx.y * 64 + wm * 32;
    const int colbase = blockIdx.x * 128 + wn * 64;

    floatx4 acc[2][4];
#pragma unroll
    for (int i = 0; i < 2; i++)
#pragma unroll
        for (int j = 0; j < 4; j++) acc[i][j] = (floatx4){0.f, 0.f, 0.f, 0.f};

#pragma unroll
    for (int kt = 0; kt < 512; kt += 32) {
        const __bf16* Aseg = (kt >= 256) ? ag : hp;
        const int ka = kt & 255;
        bf16x8 af[2], bfr[4];
#pragma unroll
        for (int mt = 0; mt < 2; mt++)
            af[mt] = *(const bf16x8*)(Aseg + (size_t)(rowbase + mt * 16 + lr) * 256 + ka + lq * 8);
#pragma unroll
        for (int nt = 0; nt < 4; nt++)
            bfr[nt] = *(const bf16x8*)(W + (size_t)(colbase + nt * 16 + lr) * 512 + kt + lq * 8);
#pragma unroll
        for (int mt = 0; mt < 2; mt++)
#pragma unroll
            for (int nt = 0; nt < 4; nt++)
                acc[mt][nt] = __builtin_amdgcn_mfma_f32_16x16x32_bf16(af[mt], bfr[nt], acc[mt][nt], 0, 0, 0);
    }

#pragma unroll
    for (int nt = 0; nt < 4; nt++) {
        const int col = colbase + nt * 16 + lr;
        const float b = bias[col];
#pragma unroll
        for (int mt = 0; mt < 2; mt++)
#pragma unroll
            for (int r = 0; r < 4; r++) {
                int row = rowbase + mt * 16 + lq * 4 + r;
                if (row < N_NODES) {
                    float res = (float)hp[(size_t)row * HID + col];
                    float v = res + fmaxf(acc[mt][nt][r] + b, 0.f);
                    hn[(size_t)row * HID + col] = (__bf16)v;
                }
            }
    }
}

// ---------------- fc GEMM + fused row L2-normalize: out = normalize(h2 @ Wfc^T) ----------------
// block 256 thr = 4 waves stacked in M; wave tile 32x128 (covers ALL output cols).

__global__ __launch_bounds__(256) void fc_norm_kernel(
    const __bf16* __restrict__ h,      // [MPAD,256] bf16
    const __bf16* __restrict__ W,      // [128,256] bf16
    float* __restrict__ out)           // [20000,128] f32
{
    const int tid = threadIdx.x;
    const int wv = tid >> 6;
    const int l = tid & 63;
    const int lr = l & 15;
    const int lq = l >> 4;
    const int rowbase = blockIdx.x * 128 + wv * 32;

    floatx4 acc[2][8];
#pragma unroll
    for (int i = 0; i < 2; i++)
#pragma unroll
        for (int j = 0; j < 8; j++) acc[i][j] = (floatx4){0.f, 0.f, 0.f, 0.f};

#pragma unroll
    for (int kt = 0; kt < 256; kt += 32) {
        bf16x8 af[2], bfr[8];
#pragma unroll
        for (int mt = 0; mt < 2; mt++)
            af[mt] = *(const bf16x8*)(h + (size_t)(rowbase + mt * 16 + lr) * 256 + kt + lq * 8);
#pragma unroll
        for (int nt = 0; nt < 8; nt++)
            bfr[nt] = *(const bf16x8*)(W + (size_t)(nt * 16 + lr) * 256 + kt + lq * 8);
#pragma unroll
        for (int mt = 0; mt < 2; mt++)
#pragma unroll
            for (int nt = 0; nt < 8; nt++)
                acc[mt][nt] = __builtin_amdgcn_mfma_f32_16x16x32_bf16(af[mt], bfr[nt], acc[mt][nt], 0, 0, 0);
    }

    // fused normalize: each output row's 128 cols live in 16 lanes (lr) x 8 regs (nt)
#pragma unroll
    for (int mt = 0; mt < 2; mt++) {
        float s[4];
#pragma unroll
        for (int r = 0; r < 4; r++) {
            float t = 0.f;
#pragma unroll
            for (int nt = 0; nt < 8; nt++) t = fmaf(acc[mt][nt][r], acc[mt][nt][r], t);
            s[r] = t;
        }
#pragma unroll
        for (int mask = 1; mask <= 8; mask <<= 1) {
#pragma unroll
            for (int r = 0; r < 4; r++) s[r] += __shfl_xor(s[r], mask);
        }
        float inv[4];
#pragma unroll
        for (int r = 0; r < 4; r++) inv[r] = rsqrtf(s[r]);
#pragma unroll
        for (int r = 0; r < 4; r++) {
            int row = rowbase + mt * 16 + lq * 4 + r;
            if (row >= N_NODES) continue;
#pragma unroll
            for (int nt = 0; nt < 8; nt++)
                out[(size_t)row * OUT_FEAT + nt * 16 + lr] = acc[mt][nt][r] * inv[r];
        }
    }
}

// ---------------- launch ----------------

extern "C" void kernel_launch(void* const* d_in, const int* in_sizes, int n_in,
                              void* d_out, int out_size, void* d_ws, size_t ws_size,
                              hipStream_t stream) {
    const float* x        = (const float*)d_in[0];
    const int*   edge_src = (const int*)d_in[1];
    const int*   edge_dst = (const int*)d_in[2];
    const float* edge_w   = (const float*)d_in[3];
    const float* W_emb    = (const float*)d_in[4];
    const float* W_gc1    = (const float*)d_in[5];
    const float* b_gc1    = (const float*)d_in[6];
    const float* W_gc2    = (const float*)d_in[7];
    const float* b_gc2    = (const float*)d_in[8];
    const float* W_fc     = (const float*)d_in[9];
    float* out = (float*)d_out;

    // ---- workspace layout ----
    char* p = (char*)d_ws;
    const size_t HROW = (size_t)MPAD * HID;
    __bf16* hb0   = (__bf16*)p;             p += HROW * 2;        // h0, later h2
    __bf16* hb1   = (__bf16*)p;             p += HROW * 2;        // h1
    __bf16* aggb  = (__bf16*)p;             p += HROW * 2;        // agg
    __bf16* wemb  = (__bf16*)p;             p += 65536 * 2;
    __bf16* w1b   = (__bf16*)p;             p += 131072 * 2;
    __bf16* w2b   = (__bf16*)p;             p += 131072 * 2;
    __bf16* wfcb  = (__bf16*)p;             p += 32768 * 2;
    int2*   edges = (int2*)p;               p += (size_t)E_EDGES * 8;
    int*    offsets = (int*)p;              p += (N_NODES + 8) * 4;
    int*    cursor  = (int*)p;              p += N_NODES * 4;
    int*    counts  = (int*)p;              p += N_NODES * 4;
    int*    bsum    = (int*)p;              p += 256 * 4;

    const int eb = (E_EDGES + 255) / 256;

    // CSR build
    zero_counts_kernel<<<NBLK, 256, 0, stream>>>(counts);
    hist_kernel<<<eb, 256, 0, stream>>>(edge_dst, counts);
    scan1_kernel<<<NBLK, 256, 0, stream>>>(counts, offsets, bsum);
    scan2_kernel<<<1, 256, 0, stream>>>(bsum);
    scan3_kernel<<<NBLK, 256, 0, stream>>>(offsets, cursor, bsum);
    scatter_kernel<<<eb, 256, 0, stream>>>(edge_src, edge_dst, edge_w, cursor, edges);

    // weight conversion
    convert_w_kernel<<<176, 256, 0, stream>>>(W_emb, W_gc1, W_gc2, W_fc, wemb, w1b, w2b, wfcb);

    const dim3 blk(256);
    const dim3 grid_g(2, MPAD / 64);         // 2 x 316 col x row blocks

    // h0 = x @ Wemb^T
    emb_gemm_kernel<<<grid_g, blk, 0, stream>>>(x, wemb, hb0);
    // agg1 = A @ h0
    aggregate_kernel<<<N_NODES / 4, blk, 0, stream>>>(hb0, offsets, edges, aggb);
    // h1 = h0 + relu([h0|agg1] @ W1^T + b1)
    gconv_gemm_kernel<<<grid_g, blk, 0, stream>>>(hb0, aggb, w1b, b_gc1, hb1);
    // agg2 = A @ h1
    aggregate_kernel<<<N_NODES / 4, blk, 0, stream>>>(hb1, offsets, edges, aggb);
    // h2 = h1 + relu([h1|agg2] @ W2^T + b2)
    gconv_gemm_kernel<<<grid_g, blk, 0, stream>>>(hb1, aggb, w2b, b_gc2, hb0);
    // out = normalize(h2 @ Wfc^T)
    fc_norm_kernel<<<MPAD / 128, blk, 0, stream>>>(hb0, wfcb, out);
}